// Round 9
// baseline (315.275 us; speedup 1.0000x reference)
//
#include <hip/hip_runtime.h>
#include <hip/hip_bf16.h>
#include <cstdint>

#define HID 128
#define GM 128          // rows per GEMM block
#define SCAN_CHUNK 2048
#define DPAD 16         // deg counter stride: one counter per 64B line

typedef __attribute__((ext_vector_type(8))) short bf16x8;
typedef __attribute__((ext_vector_type(4))) float f32x4;

__device__ __forceinline__ unsigned short f2bf(float f) {
    union { __hip_bfloat16 h; unsigned short u; } c;
    c.h = __float2bfloat16(f);
    return c.u;
}
__device__ __forceinline__ float bf2f(unsigned short u) {
    union { unsigned int i; float f; } c;
    c.i = ((unsigned int)u) << 16;
    return c.f;
}
__device__ __forceinline__ unsigned int pack2(unsigned short a, unsigned short b) {
    return (unsigned int)a | ((unsigned int)b << 16);
}
__device__ __forceinline__ bf16x8 ld_frag(const unsigned int* p) {
    union { uint4 u; bf16x8 f; } c;
    c.u = *(const uint4*)p;
    return c.f;
}

// ---------------- degree count + per-edge slot (atomic return value) ----------------
// degp padded: one counter per 64B line -> no same-line atomic serialization.
__global__ void k_count(const int* __restrict__ dst, int* __restrict__ degp,
                        int* __restrict__ slot, int n_edges) {
    int t = blockIdx.x * blockDim.x + threadIdx.x;
    int e0 = t * 8;
    if (e0 + 7 < n_edges) {
        int4 da = *(const int4*)(dst + e0);
        int4 db = *(const int4*)(dst + e0 + 4);
        int4 sa, sb;
        sa.x = atomicAdd(&degp[da.x * DPAD], 1);
        sa.y = atomicAdd(&degp[da.y * DPAD], 1);
        sa.z = atomicAdd(&degp[da.z * DPAD], 1);
        sa.w = atomicAdd(&degp[da.w * DPAD], 1);
        sb.x = atomicAdd(&degp[db.x * DPAD], 1);
        sb.y = atomicAdd(&degp[db.y * DPAD], 1);
        sb.z = atomicAdd(&degp[db.z * DPAD], 1);
        sb.w = atomicAdd(&degp[db.w * DPAD], 1);
        *(int4*)(slot + e0) = sa;       // coalesced streaming writes
        *(int4*)(slot + e0 + 4) = sb;
    } else {
        for (int e = e0; e < n_edges; ++e) slot[e] = atomicAdd(&degp[dst[e] * DPAD], 1);
    }
}

// ---------------- scan kernels ----------------
// k_scan1 used for both padded deg (stride DPAD) and flags (stride 1).
template<int STRIDE>
__global__ void k_scan1(const int* __restrict__ v_in, int* __restrict__ partials, int n) {
    __shared__ int sm[256];
    int t = threadIdx.x;
    int base = blockIdx.x * SCAN_CHUNK + t * 8;
    int s = 0;
#pragma unroll
    for (int j = 0; j < 8; ++j) { int i = base + j; if (i < n) s += v_in[(size_t)i * STRIDE]; }
    sm[t] = s;
    __syncthreads();
    for (int off = 128; off > 0; off >>= 1) {
        if (t < off) sm[t] += sm[t + off];
        __syncthreads();
    }
    if (t == 0) partials[blockIdx.x] = sm[0];
}

__global__ void k_scan2(int* partials, int nchunks, int* total) {
    int lane = threadIdx.x;  // blockDim = 64, nchunks <= 64
    int v = (lane < nchunks) ? partials[lane] : 0;
#pragma unroll
    for (int off = 1; off < 64; off <<= 1) {
        int u = __shfl_up(v, off);
        if (lane >= off) v += u;
    }
    if (total && lane == nchunks - 1) *total = v;   // grand total (inclusive)
    int ex = __shfl_up(v, 1);
    if (lane == 0) ex = 0;
    if (lane < nchunks) partials[lane] = ex;
}

__global__ void k_scan3(const int* __restrict__ degp, const int* __restrict__ partials,
                        int* __restrict__ rowptr, float* __restrict__ deg_inv, int n) {
    __shared__ int wtot[4];
    int t = threadIdx.x;
    int lane = t & 63, wv = t >> 6;
    int base = blockIdx.x * SCAN_CHUNK + t * 8;
    int v[8];
    int ts = 0;
#pragma unroll
    for (int j = 0; j < 8; ++j) { int i = base + j; v[j] = (i < n) ? degp[(size_t)i * DPAD] : 0; ts += v[j]; }
    int incl = ts;
#pragma unroll
    for (int off = 1; off < 64; off <<= 1) {
        int u = __shfl_up(incl, off);
        if (lane >= off) incl += u;
    }
    if (lane == 63) wtot[wv] = incl;
    __syncthreads();
    int woff = 0;
    for (int w = 0; w < wv; ++w) woff += wtot[w];
    int run = partials[blockIdx.x] + woff + (incl - ts);
#pragma unroll
    for (int j = 0; j < 8; ++j) {
        int i = base + j;
        run += v[j];
        if (i < n) {
            rowptr[i + 1] = run;
            deg_inv[i] = 1.0f / fmaxf((float)v[j], 1.0f);
        }
    }
    if (blockIdx.x == 0 && t == 0) rowptr[0] = 0;
}

// flags -> remap (exclusive positions) + compact node list
__global__ void k_compact(const int* __restrict__ flag, const int* __restrict__ partials,
                          int* __restrict__ remap, int* __restrict__ nodes2, int n) {
    __shared__ int wtot[4];
    int t = threadIdx.x;
    int lane = t & 63, wv = t >> 6;
    int base = blockIdx.x * SCAN_CHUNK + t * 8;
    int v[8];
    int ts = 0;
#pragma unroll
    for (int j = 0; j < 8; ++j) { int i = base + j; v[j] = (i < n) ? flag[i] : 0; ts += v[j]; }
    int incl = ts;
#pragma unroll
    for (int off = 1; off < 64; off <<= 1) {
        int u = __shfl_up(incl, off);
        if (lane >= off) incl += u;
    }
    if (lane == 63) wtot[wv] = incl;
    __syncthreads();
    int woff = 0;
    for (int w = 0; w < wv; ++w) woff += wtot[w];
    int run = partials[blockIdx.x] + woff + (incl - ts);
#pragma unroll
    for (int j = 0; j < 8; ++j) {
        int i = base + j;
        if (i < n) {
            remap[i] = run;
            if (v[j]) nodes2[run] = i;
        }
        run += v[j];
    }
}

// ---------------- CSR fill: atomic-free, writes {src, z[src]} ----------------
__global__ void k_fill(const int* __restrict__ src, const int* __restrict__ dst,
                       const int* __restrict__ slot, const int* __restrict__ rowptr,
                       const int* __restrict__ z, int2* __restrict__ csr2, int n_edges) {
    int t = blockIdx.x * blockDim.x + threadIdx.x;
    int e0 = t * 4;
    if (e0 + 3 < n_edges) {
        int4 d  = *(const int4*)(dst + e0);
        int4 s  = *(const int4*)(src + e0);
        int4 sl = *(const int4*)(slot + e0);
        int p0 = rowptr[d.x] + sl.x;
        int p1 = rowptr[d.y] + sl.y;
        int p2 = rowptr[d.z] + sl.z;
        int p3 = rowptr[d.w] + sl.w;
        csr2[p0] = make_int2(s.x, z[s.x]);
        csr2[p1] = make_int2(s.y, z[s.y]);
        csr2[p2] = make_int2(s.z, z[s.z]);
        csr2[p3] = make_int2(s.w, z[s.w]);
    } else {
        for (int e = e0; e < n_edges; ++e) {
            int se = src[e];
            csr2[rowptr[dst[e]] + slot[e]] = make_int2(se, z[se]);
        }
    }
}

// ---------------- zl = z_emb@Wl0^T ; zr = z_emb@Wr0^T + b0  (1000x128, fp32 exact) ----------------
__global__ void k_zlr(const float* __restrict__ z_emb, const float* __restrict__ Wl,
                      const float* __restrict__ Wr, const float* __restrict__ bl,
                      float* __restrict__ zl, float* __restrict__ zr, int max_z) {
    __shared__ float row[HID];
    int r = blockIdx.x;
    if (r >= max_z) return;
    int t = threadIdx.x;
    if (t < HID) row[t] = z_emb[(size_t)r * HID + t];
    __syncthreads();
    int d = t & 127;
    const float* w = (t < 128 ? Wl : Wr) + (size_t)d * HID;
    float acc = 0.f;
#pragma unroll
    for (int k4 = 0; k4 < HID / 4; ++k4) {
        float4 wv = *(const float4*)(w + k4 * 4);
        float4 hv = *(const float4*)&row[k4 * 4];
        acc += wv.x * hv.x + wv.y * hv.y + wv.z * hv.z + wv.w * hv.w;
    }
    if (t < 128) zl[(size_t)r * HID + d] = acc;
    else         zr[(size_t)r * HID + d] = acc + bl[d];
}

// ---------------- flag sel nodes and their edge sources ----------------
__global__ void k_flag(const int* __restrict__ sel, const int* __restrict__ rowptr,
                       const int2* __restrict__ csr2, int* __restrict__ flag, int n_sel) {
    int r = (blockIdx.x * blockDim.x + threadIdx.x) >> 6;
    int lane = threadIdx.x & 63;
    if (r >= n_sel) return;
    int node = sel[r];
    if (lane == 0) flag[node] = 1;
    int s = rowptr[node], e = rowptr[node + 1];
    for (int i = s + lane; i < e; i += 64) flag[csr2[i].x] = 1;
}

__global__ void k_selremap(const int* __restrict__ sel, const int* __restrict__ remap,
                           int* __restrict__ selr, int n_sel) {
    int i = blockIdx.x * blockDim.x + threadIdx.x;
    if (i < n_sel) selr[i] = remap[sel[i]];
}

// ---------------- mean aggregation: persistent waves, one wave per row ----------------
// MODE 1 (layer-1 fused): node=r, src=csr2.y (zl table), epilogue +zr[z[node]] & relu -> x1.
// MODE 2 (layer-2 compact): node=idxmap[r]=nodes2[r], src=csr2.x (x1), out compact.
// MODE 3 (layer-3): node=idxmap[r]=sel[r], src=remap[csr2.x] (x2 compact), out compact.
template<int MODE>
__global__ __launch_bounds__(256) void k_agg(const float* __restrict__ xv_,
                      float* __restrict__ aggout,
                      const int* __restrict__ rowptr, const int2* __restrict__ csr2,
                      const float* __restrict__ deg_inv, const int* __restrict__ idxmap,
                      const int* __restrict__ remap,
                      const int* __restrict__ z, const float* __restrict__ zr,
                      int n_host, const int* __restrict__ n_dev) {
    int nw_total = gridDim.x * 4;
    int w0 = blockIdx.x * 4 + (threadIdx.x >> 6);
    int lane = threadIdx.x & 63;
    int n = n_dev ? *n_dev : n_host;
    int half = lane >> 5;
    int col = lane & 31;
    const float4* xv = (const float4*)xv_;
    for (int r = w0; r < n; r += nw_total) {
        int node = (MODE == 1) ? r : idxmap[r];
        int s = rowptr[node], e = rowptr[node + 1];
        float4 a0 = {0.f,0.f,0.f,0.f}, a1 = {0.f,0.f,0.f,0.f};
        float4 a2 = {0.f,0.f,0.f,0.f}, a3 = {0.f,0.f,0.f,0.f};
        int i = s + half;
        for (; i + 6 < e; i += 8) {   // 4 rows in flight per half-wave
            int2 c0 = csr2[i];
            int2 c1 = csr2[i + 2];
            int2 c2 = csr2[i + 4];
            int2 c3 = csr2[i + 6];
            int s0 = (MODE == 1) ? c0.y : c0.x;
            int s1 = (MODE == 1) ? c1.y : c1.x;
            int s2 = (MODE == 1) ? c2.y : c2.x;
            int s3 = (MODE == 1) ? c3.y : c3.x;
            if (MODE == 3) { s0 = remap[s0]; s1 = remap[s1]; s2 = remap[s2]; s3 = remap[s3]; }
            float4 v0 = xv[(size_t)s0 * 32 + col];
            float4 v1 = xv[(size_t)s1 * 32 + col];
            float4 v2 = xv[(size_t)s2 * 32 + col];
            float4 v3 = xv[(size_t)s3 * 32 + col];
            a0.x += v0.x; a0.y += v0.y; a0.z += v0.z; a0.w += v0.w;
            a1.x += v1.x; a1.y += v1.y; a1.z += v1.z; a1.w += v1.w;
            a2.x += v2.x; a2.y += v2.y; a2.z += v2.z; a2.w += v2.w;
            a3.x += v3.x; a3.y += v3.y; a3.z += v3.z; a3.w += v3.w;
        }
        for (; i < e; i += 2) {
            int2 c0 = csr2[i];
            int s0 = (MODE == 1) ? c0.y : c0.x;
            if (MODE == 3) s0 = remap[s0];
            float4 v0 = xv[(size_t)s0 * 32 + col];
            a0.x += v0.x; a0.y += v0.y; a0.z += v0.z; a0.w += v0.w;
        }
        a0.x += a1.x + a2.x + a3.x;
        a0.y += a1.y + a2.y + a3.y;
        a0.z += a1.z + a2.z + a3.z;
        a0.w += a1.w + a2.w + a3.w;
        a0.x += __shfl_xor(a0.x, 32);
        a0.y += __shfl_xor(a0.y, 32);
        a0.z += __shfl_xor(a0.z, 32);
        a0.w += __shfl_xor(a0.w, 32);
        if (half == 0) {
            float di = deg_inv[node];
            float4 o = make_float4(a0.x * di, a0.y * di, a0.z * di, a0.w * di);
            if (MODE == 1) {
                int zn = z[node];
                float4 rv = ((const float4*)zr)[(size_t)zn * 32 + col];
                o.x = fmaxf(o.x + rv.x, 0.f);
                o.y = fmaxf(o.y + rv.y, 0.f);
                o.z = fmaxf(o.z + rv.z, 0.f);
                o.w = fmaxf(o.w + rv.w, 0.f);
            }
            ((float4*)aggout)[(size_t)r * 32 + col] = o;
        }
    }
}

// ---------------- split W into bf16 hi/lo planes, layout [l][d][k=256] ----------------
__global__ void k_wsplit(const float* __restrict__ Wl, const float* __restrict__ Wr,
                         unsigned short* __restrict__ wh, unsigned short* __restrict__ wlo) {
    int idx = blockIdx.x * blockDim.x + threadIdx.x;
    if (idx >= 3 * HID * 2 * HID) return;
    int l = idx / (HID * 2 * HID);
    int r = idx - l * (HID * 2 * HID);
    int d = r >> 8;        // 0..127
    int k = r & 255;       // 0..255
    float v = (k < HID) ? Wl[((size_t)l * HID + d) * HID + k]
                        : Wr[((size_t)l * HID + d) * HID + (k - HID)];
    unsigned short h = f2bf(v);
    unsigned short lo = f2bf(v - bf2f(h));
    wh[idx] = h;
    wlo[idx] = lo;
}

// ---------------- fused layer GEMM via split-bf16 MFMA ----------------
__global__ __launch_bounds__(256) void k_gemm(const float* __restrict__ aggsrc,
                                              const float* __restrict__ xsrc,
                                              float* __restrict__ out,
                                              const unsigned short* __restrict__ wh,
                                              const unsigned short* __restrict__ wlo,
                                              const float* __restrict__ bias,
                                              const int* __restrict__ xidx,
                                              int n_host, const int* __restrict__ n_dev,
                                              int do_relu) {
    __shared__ unsigned int sAh[GM * 16], sAl[GM * 16];
    __shared__ unsigned int sBh[HID * 16], sBl[HID * 16];
    int n_rows = n_dev ? *n_dev : n_host;
    int t = threadIdx.x;
    int node0 = blockIdx.x * GM;
    if (node0 >= n_rows) return;
    int wv = t >> 6, lane = t & 63;
    int lrow = lane & 15, lk = lane >> 4;

    f32x4 acc[2][8];
#pragma unroll
    for (int m = 0; m < 2; ++m)
#pragma unroll
        for (int n = 0; n < 8; ++n) acc[m][n] = (f32x4){0.f, 0.f, 0.f, 0.f};

    int srow = t >> 2;      // 0..63 (+64 for rr=1)
    int sq = t & 3;         // quarter of the 32-k row

    int gg[2] = {node0 + srow, node0 + srow + 64};
    bool vv[2] = {gg[0] < n_rows, gg[1] < n_rows};
    int xr[2];
#pragma unroll
    for (int rr = 0; rr < 2; ++rr)
        xr[rr] = xidx ? (vv[rr] ? xidx[gg[rr]] : 0) : gg[rr];

    for (int c = 0; c < 8; ++c) {
        int kbase = (c & 3) * 32;
        int kb = c * 32;
        // --- stage A: 128 rows x 32 k, fp32 -> split bf16 hi/lo ---
#pragma unroll
        for (int rr = 0; rr < 2; ++rr) {
            int row = srow + rr * 64;
            const float* srcrow = (c < 4) ? aggsrc + (size_t)gg[rr] * HID
                                          : xsrc + (size_t)xr[rr] * HID;
            float f[8];
            if (vv[rr]) {
                const float4* rp = (const float4*)(srcrow + kbase + sq * 8);
                float4 v0 = rp[0], v1 = rp[1];
                f[0]=v0.x; f[1]=v0.y; f[2]=v0.z; f[3]=v0.w;
                f[4]=v1.x; f[5]=v1.y; f[6]=v1.z; f[7]=v1.w;
            } else {
#pragma unroll
                for (int j = 0; j < 8; ++j) f[j] = 0.f;
            }
            unsigned int h[4], l[4];
#pragma unroll
            for (int j = 0; j < 4; ++j) {
                unsigned short h0 = f2bf(f[2*j]), h1 = f2bf(f[2*j+1]);
                unsigned short l0 = f2bf(f[2*j] - bf2f(h0));
                unsigned short l1 = f2bf(f[2*j+1] - bf2f(h1));
                h[j] = pack2(h0, h1);
                l[j] = pack2(l0, l1);
            }
            unsigned int base = row * 16 + sq * 4;
            *(uint4*)&sAh[base] = make_uint4(h[0], h[1], h[2], h[3]);
            *(uint4*)&sAl[base] = make_uint4(l[0], l[1], l[2], l[3]);
        }
        // --- stage B: 128 d-rows x 32 k, bf16 copy ---
#pragma unroll
        for (int rr = 0; rr < 2; ++rr) {
            int d = srow + rr * 64;
            size_t go = (size_t)d * 256 + kb + sq * 8;
            uint4 vh = *(const uint4*)(wh + go);
            uint4 vl = *(const uint4*)(wlo + go);
            unsigned int base = d * 16 + sq * 4;
            *(uint4*)&sBh[base] = vh;
            *(uint4*)&sBl[base] = vl;
        }
        __syncthreads();
        // --- compute: 2 M-tiles x 8 N-tiles x 3 split products ---
        bf16x8 ah0, al0, ah1, al1;
        {
            unsigned int a0 = (unsigned)(wv * 32 + lrow) * 16 + lk * 4;
            unsigned int a1 = (unsigned)(wv * 32 + 16 + lrow) * 16 + lk * 4;
            ah0 = ld_frag(&sAh[a0]); al0 = ld_frag(&sAl[a0]);
            ah1 = ld_frag(&sAh[a1]); al1 = ld_frag(&sAl[a1]);
        }
#pragma unroll
        for (int n = 0; n < 8; ++n) {
            unsigned int b = (unsigned)(n * 16 + lrow) * 16 + lk * 4;
            bf16x8 bh = ld_frag(&sBh[b]);
            bf16x8 bl = ld_frag(&sBl[b]);
            acc[0][n] = __builtin_amdgcn_mfma_f32_16x16x32_bf16(ah0, bh, acc[0][n], 0, 0, 0);
            acc[0][n] = __builtin_amdgcn_mfma_f32_16x16x32_bf16(al0, bh, acc[0][n], 0, 0, 0);
            acc[0][n] = __builtin_amdgcn_mfma_f32_16x16x32_bf16(ah0, bl, acc[0][n], 0, 0, 0);
            acc[1][n] = __builtin_amdgcn_mfma_f32_16x16x32_bf16(ah1, bh, acc[1][n], 0, 0, 0);
            acc[1][n] = __builtin_amdgcn_mfma_f32_16x16x32_bf16(al1, bh, acc[1][n], 0, 0, 0);
            acc[1][n] = __builtin_amdgcn_mfma_f32_16x16x32_bf16(ah1, bl, acc[1][n], 0, 0, 0);
        }
        __syncthreads();
    }
    // --- epilogue: bias + relu + store (D: col=lane&15, row=(lane>>4)*4+reg) ---
#pragma unroll
    for (int m = 0; m < 2; ++m) {
        int rbase = node0 + wv * 32 + m * 16 + lk * 4;
#pragma unroll
        for (int n = 0; n < 8; ++n) {
            int colb = n * 16 + lrow;
            float bb = bias[colb];
#pragma unroll
            for (int r = 0; r < 4; ++r) {
                int row = rbase + r;
                if (row < n_rows) {
                    float v = acc[m][n][r] + bb;
                    if (do_relu) v = fmaxf(v, 0.f);
                    out[(size_t)row * HID + colb] = v;
                }
            }
        }
    }
}

// ---------------- center = lower_bound(batch, g); sel rows for the last layer ----------------
__global__ void k_center(const int* __restrict__ batch, int* __restrict__ sel,
                         int n_nodes, int n_graphs) {
    int g = blockIdx.x * blockDim.x + threadIdx.x;
    if (g >= n_graphs) return;
    int lo = 0, hi = n_nodes;
    while (lo < hi) {
        int mid = (lo + hi) >> 1;
        if (batch[mid] < g) lo = mid + 1;
        else hi = mid;
    }
    sel[2 * g]     = min(lo, n_nodes - 1);      // JAX index clamp semantics
    sel[2 * g + 1] = min(lo + 1, n_nodes - 1);
}

// ---------------- readout: one wave per graph, reads compact y ----------------
__global__ void k_readout(const float* __restrict__ y,
                          const float* __restrict__ w1, const float* __restrict__ b1,
                          const float* __restrict__ w2, const float* __restrict__ b2,
                          float* __restrict__ out, int n_graphs) {
    __shared__ float h[HID];
    int g = blockIdx.x;
    if (g >= n_graphs) return;
    int lane = threadIdx.x;  // 64
    float2 a = ((const float2*)(y + (size_t)(2 * g) * HID))[lane];
    float2 b = ((const float2*)(y + (size_t)(2 * g + 1) * HID))[lane];
    h[2 * lane] = a.x * b.x;
    h[2 * lane + 1] = a.y * b.y;
    __syncthreads();
    int d0 = 2 * lane;
    float acc0 = b1[d0], acc1 = b1[d0 + 1];
    const float4* w1a = (const float4*)(w1 + (size_t)d0 * HID);
    const float4* w1b = (const float4*)(w1 + (size_t)(d0 + 1) * HID);
#pragma unroll 8
    for (int k4 = 0; k4 < HID / 4; ++k4) {
        float4 hv = *(const float4*)&h[k4 * 4];
        float4 wa = w1a[k4];
        float4 wb = w1b[k4];
        acc0 += hv.x * wa.x + hv.y * wa.y + hv.z * wa.z + hv.w * wa.w;
        acc1 += hv.x * wb.x + hv.y * wb.y + hv.z * wb.z + hv.w * wb.w;
    }
    float p = fmaxf(acc0, 0.f) * w2[d0] + fmaxf(acc1, 0.f) * w2[d0 + 1];
#pragma unroll
    for (int off = 32; off > 0; off >>= 1) p += __shfl_down(p, off);
    if (lane == 0) out[g] = p + b2[0];
}

extern "C" void kernel_launch(void* const* d_in, const int* in_sizes, int n_in,
                              void* d_out, int out_size, void* d_ws, size_t ws_size,
                              hipStream_t stream) {
    const int* z = (const int*)d_in[0];
    const int* edge_index = (const int*)d_in[1];
    const int* batch = (const int*)d_in[2];
    const float* z_emb = (const float*)d_in[4];
    const float* Wl = (const float*)d_in[5];
    const float* bl = (const float*)d_in[6];
    const float* Wr = (const float*)d_in[7];
    const float* lin1_w = (const float*)d_in[8];
    const float* lin1_b = (const float*)d_in[9];
    const float* lin2_w = (const float*)d_in[10];
    const float* lin2_b = (const float*)d_in[11];
    float* out = (float*)d_out;

    int n_nodes = in_sizes[0];
    int n_edges = in_sizes[1] / 2;
    int max_z = in_sizes[4] / HID;   // z_emb rows
    int n_graphs = out_size;         // output is [n_graphs, 1]
    int n_sel = 2 * n_graphs;

    const int* e_src = edge_index;
    const int* e_dst = edge_index + n_edges;

    char* p = (char*)d_ws;
    auto alloc = [&](size_t bytes) {
        char* r = p;
        p += (bytes + 511) & ~(size_t)511;
        return r;
    };
    float* x      = (float*)alloc((size_t)n_nodes * HID * 4);   // x1 (full)
    float* agg2   = (float*)alloc((size_t)n_nodes * HID * 4);   // layer-2 agg, compact
    float* x2c    = (float*)alloc((size_t)n_nodes * HID * 4);   // x2, compact
    float* aggsel = (float*)alloc((size_t)n_sel * HID * 4);
    float* y      = (float*)alloc((size_t)n_sel * HID * 4);
    int*   degp   = (int*)alloc((size_t)n_nodes * DPAD * 4);    // padded counters
    float* deginv = (float*)alloc((size_t)n_nodes * 4);
    int*   rowptr = (int*)alloc((size_t)(n_nodes + 1) * 4);
    int*   slot   = (int*)alloc((size_t)n_edges * 4);
    int2*  csr2   = (int2*)alloc((size_t)n_edges * 8);
    int*   parts  = (int*)alloc(64 * 4);
    int*   sel    = (int*)alloc((size_t)n_sel * 4);
    int*   selr   = (int*)alloc((size_t)n_sel * 4);
    int*   flag   = (int*)alloc((size_t)n_nodes * 4);
    int*   remap  = (int*)alloc((size_t)n_nodes * 4);
    int*   nodes2 = (int*)alloc((size_t)n_nodes * 4);
    int*   n2     = (int*)alloc(4);
    float* zl     = (float*)alloc((size_t)max_z * HID * 4);
    float* zr     = (float*)alloc((size_t)max_z * HID * 4);
    unsigned short* wh  = (unsigned short*)alloc((size_t)3 * HID * 2 * HID * 2);
    unsigned short* wlo = (unsigned short*)alloc((size_t)3 * HID * 2 * HID * 2);

    hipMemsetAsync(degp, 0, (size_t)n_nodes * DPAD * 4, stream);
    hipMemsetAsync(flag, 0, (size_t)n_nodes * 4, stream);

    k_wsplit<<<(3 * HID * 2 * HID + 255) / 256, 256, 0, stream>>>(Wl, Wr, wh, wlo);
    k_zlr<<<max_z, 256, 0, stream>>>(z_emb, Wl, Wr, bl, zl, zr, max_z);

    int n8 = (n_edges + 7) / 8;
    k_count<<<(n8 + 255) / 256, 256, 0, stream>>>(e_dst, degp, slot, n_edges);

    int nchunks = (n_nodes + SCAN_CHUNK - 1) / SCAN_CHUNK;
    k_scan1<DPAD><<<nchunks, 256, 0, stream>>>(degp, parts, n_nodes);
    k_scan2<<<1, 64, 0, stream>>>(parts, nchunks, nullptr);
    k_scan3<<<nchunks, 256, 0, stream>>>(degp, parts, rowptr, deginv, n_nodes);

    int n4 = (n_edges + 3) / 4;
    k_fill<<<(n4 + 255) / 256, 256, 0, stream>>>(e_src, e_dst, slot, rowptr, z, csr2, n_edges);
    k_center<<<(n_graphs + 255) / 256, 256, 0, stream>>>(batch, sel, n_nodes, n_graphs);

    // reachability for layer-2: sel ∪ srcs(sel edges)
    k_flag<<<(n_sel * 64 + 255) / 256, 256, 0, stream>>>(sel, rowptr, csr2, flag, n_sel);
    k_scan1<1><<<nchunks, 256, 0, stream>>>(flag, parts, n_nodes);
    k_scan2<<<1, 64, 0, stream>>>(parts, nchunks, n2);
    k_compact<<<nchunks, 256, 0, stream>>>(flag, parts, remap, nodes2, n_nodes);
    k_selremap<<<(n_sel + 255) / 256, 256, 0, stream>>>(sel, remap, selr, n_sel);

    int agg_blocks = (n_nodes + 3) / 4;
    // layer 1 (full, fused): x1 = relu(deginv * sum(zl[z_src]) + zr[z[node]])
    k_agg<1><<<agg_blocks, 256, 0, stream>>>(zl, x, rowptr, csr2, deginv, nullptr,
                                             nullptr, z, zr, n_nodes, nullptr);
    // layer 2 (compact over nodes2): persistent-stride waves, device row count
    k_agg<2><<<2048, 256, 0, stream>>>(x, agg2, rowptr, csr2, deginv, nodes2,
                                       nullptr, nullptr, nullptr, 0, n2);
    k_gemm<<<(n_nodes + GM - 1) / GM, 256, 0, stream>>>(agg2, x, x2c,
                                            wh + (size_t)HID * 2 * HID,
                                            wlo + (size_t)HID * 2 * HID,
                                            bl + HID, nodes2, 0, n2, 1);
    // layer 3: only center/center+1 rows; x2 rows fetched via remap
    k_agg<3><<<(n_sel + 3) / 4, 256, 0, stream>>>(x2c, aggsel, rowptr, csr2, deginv, sel,
                                                  remap, nullptr, nullptr, n_sel, nullptr);
    k_gemm<<<(n_sel + GM - 1) / GM, 256, 0, stream>>>(aggsel, x2c, y,
                                                      wh + (size_t)2 * HID * 2 * HID,
                                                      wlo + (size_t)2 * HID * 2 * HID,
                                                      bl + (size_t)2 * HID,
                                                      selr, n_sel, nullptr, 0);
    k_readout<<<n_graphs, 64, 0, stream>>>(y, lin1_w, lin1_b, lin2_w, lin2_b, out, n_graphs);
}

// Round 10
// 261.603 us; speedup vs baseline: 1.2052x; 1.2052x over previous
//
#include <hip/hip_runtime.h>
#include <hip/hip_bf16.h>
#include <cstdint>

#define HID 128
#define GM 128          // rows per GEMM block
#define SCAN_CHUNK 2048
#define NBIN 512        // low-9-bit buckets
#define CHUNK 2048      // edges per histogram/route block
#define MAXHI 1024      // max (n_nodes/NBIN) supported

typedef __attribute__((ext_vector_type(8))) short bf16x8;
typedef __attribute__((ext_vector_type(4))) float f32x4;

__device__ __forceinline__ unsigned short f2bf(float f) {
    union { __hip_bfloat16 h; unsigned short u; } c;
    c.h = __float2bfloat16(f);
    return c.u;
}
__device__ __forceinline__ float bf2f(unsigned short u) {
    union { unsigned int i; float f; } c;
    c.i = ((unsigned int)u) << 16;
    return c.f;
}
__device__ __forceinline__ unsigned int pack2(unsigned short a, unsigned short b) {
    return (unsigned int)a | ((unsigned int)b << 16);
}
__device__ __forceinline__ bf16x8 ld_frag(const unsigned int* p) {
    union { uint4 u; bf16x8 f; } c;
    c.u = *(const uint4*)p;
    return c.f;
}

// exclusive block scan over 256 threads (wave shfl + LDS wave totals).
// All 256 threads must participate. wtot: LDS int[4].
__device__ __forceinline__ int block_scan_excl(int v, int t, int* wtot, int* tot) {
    int lane = t & 63, wv = t >> 6;
    int incl = v;
#pragma unroll
    for (int off = 1; off < 64; off <<= 1) {
        int u = __shfl_up(incl, off);
        if (lane >= off) incl += u;
    }
    if (lane == 63) wtot[wv] = incl;
    __syncthreads();
    int woff = 0;
    for (int w = 0; w < wv; ++w) woff += wtot[w];
    if (tot) *tot = wtot[0] + wtot[1] + wtot[2] + wtot[3];
    __syncthreads();   // allow wtot reuse
    return woff + incl - v;
}

// ---------------- pass 1a: per-block 512-bin histogram of dst low bits ----------------
__global__ __launch_bounds__(256) void k_hist(const int* __restrict__ dst,
                                              int* __restrict__ hist, int n_edges) {
    __shared__ int h[NBIN];
    int t = threadIdx.x;
    h[t] = 0; h[t + 256] = 0;
    __syncthreads();
    int base = blockIdx.x * CHUNK;
#pragma unroll
    for (int j = 0; j < CHUNK / 256; ++j) {
        int e = base + j * 256 + t;
        if (e < n_edges) atomicAdd(&h[dst[e] & (NBIN - 1)], 1);
    }
    __syncthreads();
    hist[(size_t)blockIdx.x * NBIN + t] = h[t];
    hist[(size_t)blockIdx.x * NBIN + t + 256] = h[t + 256];
}

// ---------------- pass 1b: per-bin exclusive scan over blocks (in place) ----------------
__global__ __launch_bounds__(256) void k_colscan(int* __restrict__ hist,
                                                 int* __restrict__ bintotal, int B) {
    __shared__ int wtot[4];
    int k = blockIdx.x, t = threadIdx.x;
    int run = 0;
    for (int base = 0; base < B; base += 256) {
        int b = base + t;
        int v = (b < B) ? hist[(size_t)b * NBIN + k] : 0;
        int tot;
        int excl = block_scan_excl(v, t, wtot, &tot);
        if (b < B) hist[(size_t)b * NBIN + k] = run + excl;
        run += tot;
    }
    if (t == 0) bintotal[k] = run;
}

// ---------------- pass 1c: exclusive scan of 512 bin totals ----------------
__global__ __launch_bounds__(256) void k_binbase(const int* __restrict__ bintotal,
                                                 int* __restrict__ binbase) {
    __shared__ int wtot[4];
    int t = threadIdx.x;
    int a0 = bintotal[2 * t], a1 = bintotal[2 * t + 1];
    int excl = block_scan_excl(a0 + a1, t, wtot, nullptr);
    binbase[2 * t] = excl;
    binbase[2 * t + 1] = excl + a0;
    if (t == 255) binbase[NBIN] = excl + a0 + a1;
}

// ---------------- pass 1d: route edges into bin regions (LDS ranks, no global atomics) --
__global__ __launch_bounds__(256) void k_route(const int* __restrict__ src,
                                               const int* __restrict__ dst,
                                               const int* __restrict__ histex,
                                               const int* __restrict__ binbase,
                                               int2* __restrict__ ebuf, int n_edges) {
    __shared__ int h2[NBIN];
    __shared__ int basel[NBIN];
    int t = threadIdx.x;
    h2[t] = 0; h2[t + 256] = 0;
    basel[t]       = binbase[t]       + histex[(size_t)blockIdx.x * NBIN + t];
    basel[t + 256] = binbase[t + 256] + histex[(size_t)blockIdx.x * NBIN + t + 256];
    __syncthreads();
    int base = blockIdx.x * CHUNK;
#pragma unroll
    for (int j = 0; j < CHUNK / 256; ++j) {
        int e = base + j * 256 + t;
        if (e < n_edges) {
            int d = dst[e], s = src[e];
            int bin = d & (NBIN - 1);
            int r = atomicAdd(&h2[bin], 1);
            ebuf[basel[bin] + r] = make_int2(s, d);
        }
    }
}

// ---------------- pass 2: exact grouping by node within each bin region ----------------
// Emits start[node], deg[node], and node-grouped csr2 = {src, z[src]}.
__global__ __launch_bounds__(256) void k_group(const int2* __restrict__ ebuf,
                                               const int* __restrict__ binbase,
                                               const int* __restrict__ z,
                                               int2* __restrict__ csr2,
                                               int* __restrict__ start, int* __restrict__ deg,
                                               int n_nodes) {
    __shared__ int hh[MAXHI];
    __shared__ int cur[MAXHI];
    __shared__ int wtot[4];
    int k = blockIdx.x, t = threadIdx.x;
    int rs = binbase[k], re = binbase[k + 1];
#pragma unroll
    for (int j = 0; j < MAXHI / 256; ++j) hh[t + j * 256] = 0;
    __syncthreads();
    for (int i = rs + t; i < re; i += 256)
        atomicAdd(&hh[ebuf[i].y >> 9], 1);
    __syncthreads();
    int idx = t * 4;
    int a0 = hh[idx], a1 = hh[idx + 1], a2 = hh[idx + 2], a3 = hh[idx + 3];
    int excl = block_scan_excl(a0 + a1 + a2 + a3, t, wtot, nullptr);
    int e0 = excl, e1 = e0 + a0, e2 = e1 + a1, e3 = e2 + a2;
    cur[idx] = e0; cur[idx + 1] = e1; cur[idx + 2] = e2; cur[idx + 3] = e3;
    int ee[4] = {e0, e1, e2, e3};
    int aa[4] = {a0, a1, a2, a3};
#pragma unroll
    for (int j = 0; j < 4; ++j) {
        int node = ((idx + j) << 9) | k;
        if (node < n_nodes) {
            start[node] = rs + ee[j];
            deg[node] = aa[j];
        }
    }
    __syncthreads();
    for (int i = rs + t; i < re; i += 256) {
        int2 sd = ebuf[i];
        int r = atomicAdd(&cur[sd.y >> 9], 1);
        csr2[rs + r] = make_int2(sd.x, z[sd.x]);
    }
}

// ---------------- flag scan kernels (layer-2 compaction) ----------------
__global__ void k_scan1(const int* __restrict__ v_in, int* __restrict__ partials, int n) {
    __shared__ int sm[256];
    int t = threadIdx.x;
    int base = blockIdx.x * SCAN_CHUNK + t * 8;
    int s = 0;
#pragma unroll
    for (int j = 0; j < 8; ++j) { int i = base + j; if (i < n) s += v_in[i]; }
    sm[t] = s;
    __syncthreads();
    for (int off = 128; off > 0; off >>= 1) {
        if (t < off) sm[t] += sm[t + off];
        __syncthreads();
    }
    if (t == 0) partials[blockIdx.x] = sm[0];
}

__global__ void k_scan2(int* partials, int nchunks, int* total) {
    int lane = threadIdx.x;  // blockDim = 64, nchunks <= 64
    int v = (lane < nchunks) ? partials[lane] : 0;
#pragma unroll
    for (int off = 1; off < 64; off <<= 1) {
        int u = __shfl_up(v, off);
        if (lane >= off) v += u;
    }
    if (total && lane == nchunks - 1) *total = v;
    int ex = __shfl_up(v, 1);
    if (lane == 0) ex = 0;
    if (lane < nchunks) partials[lane] = ex;
}

__global__ void k_compact(const int* __restrict__ flag, const int* __restrict__ partials,
                          int* __restrict__ remap, int* __restrict__ nodes2, int n) {
    __shared__ int wtot[4];
    int t = threadIdx.x;
    int lane = t & 63, wv = t >> 6;
    int base = blockIdx.x * SCAN_CHUNK + t * 8;
    int v[8];
    int ts = 0;
#pragma unroll
    for (int j = 0; j < 8; ++j) { int i = base + j; v[j] = (i < n) ? flag[i] : 0; ts += v[j]; }
    int incl = ts;
#pragma unroll
    for (int off = 1; off < 64; off <<= 1) {
        int u = __shfl_up(incl, off);
        if (lane >= off) incl += u;
    }
    if (lane == 63) wtot[wv] = incl;
    __syncthreads();
    int woff = 0;
    for (int w = 0; w < wv; ++w) woff += wtot[w];
    int run = partials[blockIdx.x] + woff + (incl - ts);
#pragma unroll
    for (int j = 0; j < 8; ++j) {
        int i = base + j;
        if (i < n) {
            remap[i] = run;
            if (v[j]) nodes2[run] = i;
        }
        run += v[j];
    }
}

// ---------------- zl = z_emb@Wl0^T ; zr = z_emb@Wr0^T + b0  (1000x128, fp32 exact) ----------------
__global__ void k_zlr(const float* __restrict__ z_emb, const float* __restrict__ Wl,
                      const float* __restrict__ Wr, const float* __restrict__ bl,
                      float* __restrict__ zl, float* __restrict__ zr, int max_z) {
    __shared__ float row[HID];
    int r = blockIdx.x;
    if (r >= max_z) return;
    int t = threadIdx.x;
    if (t < HID) row[t] = z_emb[(size_t)r * HID + t];
    __syncthreads();
    int d = t & 127;
    const float* w = (t < 128 ? Wl : Wr) + (size_t)d * HID;
    float acc = 0.f;
#pragma unroll
    for (int k4 = 0; k4 < HID / 4; ++k4) {
        float4 wv = *(const float4*)(w + k4 * 4);
        float4 hv = *(const float4*)&row[k4 * 4];
        acc += wv.x * hv.x + wv.y * hv.y + wv.z * hv.z + wv.w * hv.w;
    }
    if (t < 128) zl[(size_t)r * HID + d] = acc;
    else         zr[(size_t)r * HID + d] = acc + bl[d];
}

// ---------------- flag sel nodes and their edge sources ----------------
__global__ void k_flag(const int* __restrict__ sel, const int* __restrict__ start,
                       const int* __restrict__ deg,
                       const int2* __restrict__ csr2, int* __restrict__ flag, int n_sel) {
    int r = (blockIdx.x * blockDim.x + threadIdx.x) >> 6;
    int lane = threadIdx.x & 63;
    if (r >= n_sel) return;
    int node = sel[r];
    if (lane == 0) flag[node] = 1;
    int s = start[node], e = s + deg[node];
    for (int i = s + lane; i < e; i += 64) flag[csr2[i].x] = 1;
}

__global__ void k_selremap(const int* __restrict__ sel, const int* __restrict__ remap,
                           int* __restrict__ selr, int n_sel) {
    int i = blockIdx.x * blockDim.x + threadIdx.x;
    if (i < n_sel) selr[i] = remap[sel[i]];
}

// ---------------- mean aggregation: persistent waves, one wave per row ----------------
// MODE 1 (layer-1 fused): node=r, src=csr2.y (zl table), epilogue +zr[z[node]] & relu -> x1.
// MODE 2 (layer-2 compact): node=idxmap[r]=nodes2[r], src=csr2.x (x1), out compact.
// MODE 3 (layer-3): node=idxmap[r]=sel[r], src=remap[csr2.x] (x2 compact), out compact.
template<int MODE>
__global__ __launch_bounds__(256) void k_agg(const float* __restrict__ xv_,
                      float* __restrict__ aggout,
                      const int* __restrict__ start, const int* __restrict__ deg,
                      const int2* __restrict__ csr2,
                      const int* __restrict__ idxmap, const int* __restrict__ remap,
                      const int* __restrict__ z, const float* __restrict__ zr,
                      int n_host, const int* __restrict__ n_dev) {
    int nw_total = gridDim.x * 4;
    int w0 = blockIdx.x * 4 + (threadIdx.x >> 6);
    int lane = threadIdx.x & 63;
    int n = n_dev ? *n_dev : n_host;
    int half = lane >> 5;
    int col = lane & 31;
    const float4* xv = (const float4*)xv_;
    for (int r = w0; r < n; r += nw_total) {
        int node = (MODE == 1) ? r : idxmap[r];
        int s = start[node];
        int dg = deg[node];
        int e = s + dg;
        float4 a0 = {0.f,0.f,0.f,0.f}, a1 = {0.f,0.f,0.f,0.f};
        float4 a2 = {0.f,0.f,0.f,0.f}, a3 = {0.f,0.f,0.f,0.f};
        int i = s + half;
        for (; i + 6 < e; i += 8) {   // 4 rows in flight per half-wave
            int2 c0 = csr2[i];
            int2 c1 = csr2[i + 2];
            int2 c2 = csr2[i + 4];
            int2 c3 = csr2[i + 6];
            int s0 = (MODE == 1) ? c0.y : c0.x;
            int s1 = (MODE == 1) ? c1.y : c1.x;
            int s2 = (MODE == 1) ? c2.y : c2.x;
            int s3 = (MODE == 1) ? c3.y : c3.x;
            if (MODE == 3) { s0 = remap[s0]; s1 = remap[s1]; s2 = remap[s2]; s3 = remap[s3]; }
            float4 v0 = xv[(size_t)s0 * 32 + col];
            float4 v1 = xv[(size_t)s1 * 32 + col];
            float4 v2 = xv[(size_t)s2 * 32 + col];
            float4 v3 = xv[(size_t)s3 * 32 + col];
            a0.x += v0.x; a0.y += v0.y; a0.z += v0.z; a0.w += v0.w;
            a1.x += v1.x; a1.y += v1.y; a1.z += v1.z; a1.w += v1.w;
            a2.x += v2.x; a2.y += v2.y; a2.z += v2.z; a2.w += v2.w;
            a3.x += v3.x; a3.y += v3.y; a3.z += v3.z; a3.w += v3.w;
        }
        for (; i < e; i += 2) {
            int2 c0 = csr2[i];
            int s0 = (MODE == 1) ? c0.y : c0.x;
            if (MODE == 3) s0 = remap[s0];
            float4 v0 = xv[(size_t)s0 * 32 + col];
            a0.x += v0.x; a0.y += v0.y; a0.z += v0.z; a0.w += v0.w;
        }
        a0.x += a1.x + a2.x + a3.x;
        a0.y += a1.y + a2.y + a3.y;
        a0.z += a1.z + a2.z + a3.z;
        a0.w += a1.w + a2.w + a3.w;
        a0.x += __shfl_xor(a0.x, 32);
        a0.y += __shfl_xor(a0.y, 32);
        a0.z += __shfl_xor(a0.z, 32);
        a0.w += __shfl_xor(a0.w, 32);
        if (half == 0) {
            float di = 1.0f / fmaxf((float)dg, 1.0f);
            float4 o = make_float4(a0.x * di, a0.y * di, a0.z * di, a0.w * di);
            if (MODE == 1) {
                int zn = z[node];
                float4 rv = ((const float4*)zr)[(size_t)zn * 32 + col];
                o.x = fmaxf(o.x + rv.x, 0.f);
                o.y = fmaxf(o.y + rv.y, 0.f);
                o.z = fmaxf(o.z + rv.z, 0.f);
                o.w = fmaxf(o.w + rv.w, 0.f);
            }
            ((float4*)aggout)[(size_t)r * 32 + col] = o;
        }
    }
}

// ---------------- split W into bf16 hi/lo planes, layout [l][d][k=256] ----------------
__global__ void k_wsplit(const float* __restrict__ Wl, const float* __restrict__ Wr,
                         unsigned short* __restrict__ wh, unsigned short* __restrict__ wlo) {
    int idx = blockIdx.x * blockDim.x + threadIdx.x;
    if (idx >= 3 * HID * 2 * HID) return;
    int l = idx / (HID * 2 * HID);
    int r = idx - l * (HID * 2 * HID);
    int d = r >> 8;        // 0..127
    int k = r & 255;       // 0..255
    float v = (k < HID) ? Wl[((size_t)l * HID + d) * HID + k]
                        : Wr[((size_t)l * HID + d) * HID + (k - HID)];
    unsigned short h = f2bf(v);
    unsigned short lo = f2bf(v - bf2f(h));
    wh[idx] = h;
    wlo[idx] = lo;
}

// ---------------- fused layer GEMM via split-bf16 MFMA ----------------
__global__ __launch_bounds__(256) void k_gemm(const float* __restrict__ aggsrc,
                                              const float* __restrict__ xsrc,
                                              float* __restrict__ out,
                                              const unsigned short* __restrict__ wh,
                                              const unsigned short* __restrict__ wlo,
                                              const float* __restrict__ bias,
                                              const int* __restrict__ xidx,
                                              int n_host, const int* __restrict__ n_dev,
                                              int do_relu) {
    __shared__ unsigned int sAh[GM * 16], sAl[GM * 16];
    __shared__ unsigned int sBh[HID * 16], sBl[HID * 16];
    int n_rows = n_dev ? *n_dev : n_host;
    int t = threadIdx.x;
    int node0 = blockIdx.x * GM;
    if (node0 >= n_rows) return;
    int wv = t >> 6, lane = t & 63;
    int lrow = lane & 15, lk = lane >> 4;

    f32x4 acc[2][8];
#pragma unroll
    for (int m = 0; m < 2; ++m)
#pragma unroll
        for (int n = 0; n < 8; ++n) acc[m][n] = (f32x4){0.f, 0.f, 0.f, 0.f};

    int srow = t >> 2;      // 0..63 (+64 for rr=1)
    int sq = t & 3;         // quarter of the 32-k row

    int gg[2] = {node0 + srow, node0 + srow + 64};
    bool vv[2] = {gg[0] < n_rows, gg[1] < n_rows};
    int xr[2];
#pragma unroll
    for (int rr = 0; rr < 2; ++rr)
        xr[rr] = xidx ? (vv[rr] ? xidx[gg[rr]] : 0) : gg[rr];

    for (int c = 0; c < 8; ++c) {
        int kbase = (c & 3) * 32;
        int kb = c * 32;
        // --- stage A: 128 rows x 32 k, fp32 -> split bf16 hi/lo ---
#pragma unroll
        for (int rr = 0; rr < 2; ++rr) {
            int row = srow + rr * 64;
            const float* srcrow = (c < 4) ? aggsrc + (size_t)gg[rr] * HID
                                          : xsrc + (size_t)xr[rr] * HID;
            float f[8];
            if (vv[rr]) {
                const float4* rp = (const float4*)(srcrow + kbase + sq * 8);
                float4 v0 = rp[0], v1 = rp[1];
                f[0]=v0.x; f[1]=v0.y; f[2]=v0.z; f[3]=v0.w;
                f[4]=v1.x; f[5]=v1.y; f[6]=v1.z; f[7]=v1.w;
            } else {
#pragma unroll
                for (int j = 0; j < 8; ++j) f[j] = 0.f;
            }
            unsigned int h[4], l[4];
#pragma unroll
            for (int j = 0; j < 4; ++j) {
                unsigned short h0 = f2bf(f[2*j]), h1 = f2bf(f[2*j+1]);
                unsigned short l0 = f2bf(f[2*j] - bf2f(h0));
                unsigned short l1 = f2bf(f[2*j+1] - bf2f(h1));
                h[j] = pack2(h0, h1);
                l[j] = pack2(l0, l1);
            }
            unsigned int base = row * 16 + sq * 4;
            *(uint4*)&sAh[base] = make_uint4(h[0], h[1], h[2], h[3]);
            *(uint4*)&sAl[base] = make_uint4(l[0], l[1], l[2], l[3]);
        }
        // --- stage B: 128 d-rows x 32 k, bf16 copy ---
#pragma unroll
        for (int rr = 0; rr < 2; ++rr) {
            int d = srow + rr * 64;
            size_t go = (size_t)d * 256 + kb + sq * 8;
            uint4 vh = *(const uint4*)(wh + go);
            uint4 vl = *(const uint4*)(wlo + go);
            unsigned int base = d * 16 + sq * 4;
            *(uint4*)&sBh[base] = vh;
            *(uint4*)&sBl[base] = vl;
        }
        __syncthreads();
        // --- compute: 2 M-tiles x 8 N-tiles x 3 split products ---
        bf16x8 ah0, al0, ah1, al1;
        {
            unsigned int a0 = (unsigned)(wv * 32 + lrow) * 16 + lk * 4;
            unsigned int a1 = (unsigned)(wv * 32 + 16 + lrow) * 16 + lk * 4;
            ah0 = ld_frag(&sAh[a0]); al0 = ld_frag(&sAl[a0]);
            ah1 = ld_frag(&sAh[a1]); al1 = ld_frag(&sAl[a1]);
        }
#pragma unroll
        for (int n = 0; n < 8; ++n) {
            unsigned int b = (unsigned)(n * 16 + lrow) * 16 + lk * 4;
            bf16x8 bh = ld_frag(&sBh[b]);
            bf16x8 bl = ld_frag(&sBl[b]);
            acc[0][n] = __builtin_amdgcn_mfma_f32_16x16x32_bf16(ah0, bh, acc[0][n], 0, 0, 0);
            acc[0][n] = __builtin_amdgcn_mfma_f32_16x16x32_bf16(al0, bh, acc[0][n], 0, 0, 0);
            acc[0][n] = __builtin_amdgcn_mfma_f32_16x16x32_bf16(ah0, bl, acc[0][n], 0, 0, 0);
            acc[1][n] = __builtin_amdgcn_mfma_f32_16x16x32_bf16(ah1, bh, acc[1][n], 0, 0, 0);
            acc[1][n] = __builtin_amdgcn_mfma_f32_16x16x32_bf16(al1, bh, acc[1][n], 0, 0, 0);
            acc[1][n] = __builtin_amdgcn_mfma_f32_16x16x32_bf16(ah1, bl, acc[1][n], 0, 0, 0);
        }
        __syncthreads();
    }
    // --- epilogue: bias + relu + store (D: col=lane&15, row=(lane>>4)*4+reg) ---
#pragma unroll
    for (int m = 0; m < 2; ++m) {
        int rbase = node0 + wv * 32 + m * 16 + lk * 4;
#pragma unroll
        for (int n = 0; n < 8; ++n) {
            int colb = n * 16 + lrow;
            float bb = bias[colb];
#pragma unroll
            for (int r = 0; r < 4; ++r) {
                int row = rbase + r;
                if (row < n_rows) {
                    float v = acc[m][n][r] + bb;
                    if (do_relu) v = fmaxf(v, 0.f);
                    out[(size_t)row * HID + colb] = v;
                }
            }
        }
    }
}

// ---------------- center = lower_bound(batch, g); sel rows for the last layer ----------------
__global__ void k_center(const int* __restrict__ batch, int* __restrict__ sel,
                         int n_nodes, int n_graphs) {
    int g = blockIdx.x * blockDim.x + threadIdx.x;
    if (g >= n_graphs) return;
    int lo = 0, hi = n_nodes;
    while (lo < hi) {
        int mid = (lo + hi) >> 1;
        if (batch[mid] < g) lo = mid + 1;
        else hi = mid;
    }
    sel[2 * g]     = min(lo, n_nodes - 1);      // JAX index clamp semantics
    sel[2 * g + 1] = min(lo + 1, n_nodes - 1);
}

// ---------------- readout: one wave per graph, reads compact y ----------------
__global__ void k_readout(const float* __restrict__ y,
                          const float* __restrict__ w1, const float* __restrict__ b1,
                          const float* __restrict__ w2, const float* __restrict__ b2,
                          float* __restrict__ out, int n_graphs) {
    __shared__ float h[HID];
    int g = blockIdx.x;
    if (g >= n_graphs) return;
    int lane = threadIdx.x;  // 64
    float2 a = ((const float2*)(y + (size_t)(2 * g) * HID))[lane];
    float2 b = ((const float2*)(y + (size_t)(2 * g + 1) * HID))[lane];
    h[2 * lane] = a.x * b.x;
    h[2 * lane + 1] = a.y * b.y;
    __syncthreads();
    int d0 = 2 * lane;
    float acc0 = b1[d0], acc1 = b1[d0 + 1];
    const float4* w1a = (const float4*)(w1 + (size_t)d0 * HID);
    const float4* w1b = (const float4*)(w1 + (size_t)(d0 + 1) * HID);
#pragma unroll 8
    for (int k4 = 0; k4 < HID / 4; ++k4) {
        float4 hv = *(const float4*)&h[k4 * 4];
        float4 wa = w1a[k4];
        float4 wb = w1b[k4];
        acc0 += hv.x * wa.x + hv.y * wa.y + hv.z * wa.z + hv.w * wa.w;
        acc1 += hv.x * wb.x + hv.y * wb.y + hv.z * wb.z + hv.w * wb.w;
    }
    float p = fmaxf(acc0, 0.f) * w2[d0] + fmaxf(acc1, 0.f) * w2[d0 + 1];
#pragma unroll
    for (int off = 32; off > 0; off >>= 1) p += __shfl_down(p, off);
    if (lane == 0) out[g] = p + b2[0];
}

extern "C" void kernel_launch(void* const* d_in, const int* in_sizes, int n_in,
                              void* d_out, int out_size, void* d_ws, size_t ws_size,
                              hipStream_t stream) {
    const int* z = (const int*)d_in[0];
    const int* edge_index = (const int*)d_in[1];
    const int* batch = (const int*)d_in[2];
    const float* z_emb = (const float*)d_in[4];
    const float* Wl = (const float*)d_in[5];
    const float* bl = (const float*)d_in[6];
    const float* Wr = (const float*)d_in[7];
    const float* lin1_w = (const float*)d_in[8];
    const float* lin1_b = (const float*)d_in[9];
    const float* lin2_w = (const float*)d_in[10];
    const float* lin2_b = (const float*)d_in[11];
    float* out = (float*)d_out;

    int n_nodes = in_sizes[0];
    int n_edges = in_sizes[1] / 2;
    int max_z = in_sizes[4] / HID;   // z_emb rows
    int n_graphs = out_size;         // output is [n_graphs, 1]
    int n_sel = 2 * n_graphs;

    const int* e_src = edge_index;
    const int* e_dst = edge_index + n_edges;

    char* p = (char*)d_ws;
    auto alloc = [&](size_t bytes) {
        char* r = p;
        p += (bytes + 511) & ~(size_t)511;
        return r;
    };
    float* x      = (float*)alloc((size_t)n_nodes * HID * 4);   // x1 (full)
    float* agg2   = (float*)alloc((size_t)n_nodes * HID * 4);   // layer-2 agg, compact
    float* x2c    = (float*)alloc((size_t)n_nodes * HID * 4);   // x2, compact
    float* aggsel = (float*)alloc((size_t)n_sel * HID * 4);
    float* y      = (float*)alloc((size_t)n_sel * HID * 4);
    int*   deg    = (int*)alloc((size_t)n_nodes * 4);
    int*   start  = (int*)alloc((size_t)n_nodes * 4);
    int2*  ebuf   = (int2*)alloc((size_t)n_edges * 8);
    int2*  csr2   = (int2*)alloc((size_t)n_edges * 8);
    int B = (n_edges + CHUNK - 1) / CHUNK;
    int*   hist     = (int*)alloc((size_t)B * NBIN * 4);
    int*   bintotal = (int*)alloc((size_t)NBIN * 4);
    int*   binbase  = (int*)alloc((size_t)(NBIN + 1) * 4);
    int*   parts  = (int*)alloc(64 * 4);
    int*   sel    = (int*)alloc((size_t)n_sel * 4);
    int*   selr   = (int*)alloc((size_t)n_sel * 4);
    int*   flag   = (int*)alloc((size_t)n_nodes * 4);
    int*   remap  = (int*)alloc((size_t)n_nodes * 4);
    int*   nodes2 = (int*)alloc((size_t)n_nodes * 4);
    int*   n2     = (int*)alloc(4);
    float* zl     = (float*)alloc((size_t)max_z * HID * 4);
    float* zr     = (float*)alloc((size_t)max_z * HID * 4);
    unsigned short* wh  = (unsigned short*)alloc((size_t)3 * HID * 2 * HID * 2);
    unsigned short* wlo = (unsigned short*)alloc((size_t)3 * HID * 2 * HID * 2);

    hipMemsetAsync(flag, 0, (size_t)n_nodes * 4, stream);

    k_wsplit<<<(3 * HID * 2 * HID + 255) / 256, 256, 0, stream>>>(Wl, Wr, wh, wlo);
    k_zlr<<<max_z, 256, 0, stream>>>(z_emb, Wl, Wr, bl, zl, zr, max_z);

    // ---- atomic-free CSR build: 2-level counting sort ----
    k_hist<<<B, 256, 0, stream>>>(e_dst, hist, n_edges);
    k_colscan<<<NBIN, 256, 0, stream>>>(hist, bintotal, B);
    k_binbase<<<1, 256, 0, stream>>>(bintotal, binbase);
    k_route<<<B, 256, 0, stream>>>(e_src, e_dst, hist, binbase, ebuf, n_edges);
    k_group<<<NBIN, 256, 0, stream>>>(ebuf, binbase, z, csr2, start, deg, n_nodes);

    k_center<<<(n_graphs + 255) / 256, 256, 0, stream>>>(batch, sel, n_nodes, n_graphs);

    // reachability for layer-2: sel ∪ srcs(sel edges)
    k_flag<<<(n_sel * 64 + 255) / 256, 256, 0, stream>>>(sel, start, deg, csr2, flag, n_sel);
    int nchunks = (n_nodes + SCAN_CHUNK - 1) / SCAN_CHUNK;
    k_scan1<<<nchunks, 256, 0, stream>>>(flag, parts, n_nodes);
    k_scan2<<<1, 64, 0, stream>>>(parts, nchunks, n2);
    k_compact<<<nchunks, 256, 0, stream>>>(flag, parts, remap, nodes2, n_nodes);
    k_selremap<<<(n_sel + 255) / 256, 256, 0, stream>>>(sel, remap, selr, n_sel);

    int agg_blocks = (n_nodes + 3) / 4;
    // layer 1 (full, fused): x1 = relu(deginv * sum(zl[z_src]) + zr[z[node]])
    k_agg<1><<<agg_blocks, 256, 0, stream>>>(zl, x, start, deg, csr2, nullptr,
                                             nullptr, z, zr, n_nodes, nullptr);
    // layer 2 (compact over nodes2): persistent-stride waves, device row count
    k_agg<2><<<2048, 256, 0, stream>>>(x, agg2, start, deg, csr2, nodes2,
                                       nullptr, nullptr, nullptr, 0, n2);
    k_gemm<<<(n_nodes + GM - 1) / GM, 256, 0, stream>>>(agg2, x, x2c,
                                            wh + (size_t)HID * 2 * HID,
                                            wlo + (size_t)HID * 2 * HID,
                                            bl + HID, nodes2, 0, n2, 1);
    // layer 3: only center/center+1 rows; x2 rows fetched via remap
    k_agg<3><<<(n_sel + 3) / 4, 256, 0, stream>>>(x2c, aggsel, start, deg, csr2, sel,
                                                  remap, nullptr, nullptr, n_sel, nullptr);
    k_gemm<<<(n_sel + GM - 1) / GM, 256, 0, stream>>>(aggsel, x2c, y,
                                                      wh + (size_t)2 * HID * 2 * HID,
                                                      wlo + (size_t)2 * HID * 2 * HID,
                                                      bl + (size_t)2 * HID,
                                                      selr, n_sel, nullptr, 0);
    k_readout<<<n_graphs, 64, 0, stream>>>(y, lin1_w, lin1_b, lin2_w, lin2_b, out, n_graphs);
}